// Round 12
// baseline (10836.286 us; speedup 1.0000x reference)
//
#include <hip/hip_runtime.h>

// Problem constants (B=16, N=M=1024, D=32)
constexpr int   NN       = 1024;
constexpr float EPSf     = 1e-3f;
constexpr int   MAX_ITER = 100;

#define K2      1442.6950408889634f     // (1/eps) * log2(e)
#define LN2f    0.6931471805599453f
#define LOGK    (-6.9314616f)           // log(1/1024 + 1e-8)
#define LOGK2   (-9.9999852269f)        // LOGK * log2(e)

#define EXP2F(x) __builtin_amdgcn_exp2f(x)   // 2^x
#define LOG2F(x) __builtin_amdgcn_logf(x)    // log2(x)

typedef _Float16 half8 __attribute__((ext_vector_type(8)));

// ---------------------------------------------------------------------------
// dist[b][p][q] = sum_d (A[b][p][d] - Bm[b][q][d])^2, stored fp16 (validated)
// ---------------------------------------------------------------------------
__global__ __launch_bounds__(256) void build_dist(
    const float* __restrict__ A, const float* __restrict__ Bm,
    _Float16* __restrict__ out)
{
    __shared__ float aLds[16 * 32];
    __shared__ float bLds[256 * 33];
    const int b  = blockIdx.x >> 6;
    const int pt = blockIdx.x & 63;
    const int t  = threadIdx.x;

    const float* Ab = A  + ((size_t)b * NN + pt * 16) * 32;
    const float* Bb = Bm + (size_t)b * NN * 32;

    if (t < 128) ((float4*)aLds)[t] = ((const float4*)Ab)[t];

    for (int qt = 0; qt < 4; ++qt) {
        __syncthreads();
        const float4* src = (const float4*)(Bb + qt * 256 * 32);
#pragma unroll
        for (int i = 0; i < 8; ++i) {
            int j = t + (i << 8);
            float4 val = src[j];
            int q = j >> 3, dd = (j & 7) << 2;
            float* dst = &bLds[q * 33 + dd];
            dst[0] = val.x; dst[1] = val.y; dst[2] = val.z; dst[3] = val.w;
        }
        __syncthreads();

        float br[32];
#pragma unroll
        for (int d = 0; d < 32; ++d) br[d] = bLds[t * 33 + d];

#pragma unroll
        for (int p = 0; p < 16; ++p) {
            float acc = 0.f;
#pragma unroll
            for (int d4 = 0; d4 < 8; ++d4) {
                float4 a4 = ((const float4*)(aLds + p * 32))[d4];
                float dx = a4.x - br[d4 * 4 + 0];
                float dy = a4.y - br[d4 * 4 + 1];
                float dz = a4.z - br[d4 * 4 + 2];
                float dw = a4.w - br[d4 * 4 + 3];
                acc += dx * dx + dy * dy + dz * dz + dw * dw;
            }
            out[((size_t)b * NN + pt * 16 + p) * NN + qt * 256 + t] = (_Float16)acc;
        }
    }
}

// ---------------------------------------------------------------------------
// Sense-reversing barrier over the 32 blocks of one batch (tid 0 spins).
// __threadfence = agent-scope fence (L2 writeback + L1 inv on gfx950) ->
// u/v stores are visible to the batch's other blocks even cross-XCD.
// ---------------------------------------------------------------------------
__device__ __forceinline__ void group_barrier(int* cnt, int* gen)
{
    __syncthreads();
    if (threadIdx.x == 0) {
        __threadfence();   // release
        int g = __hip_atomic_load(gen, __ATOMIC_RELAXED, __HIP_MEMORY_SCOPE_AGENT);
        int a = __hip_atomic_fetch_add(cnt, 1, __ATOMIC_ACQ_REL, __HIP_MEMORY_SCOPE_AGENT);
        if (a == 31) {
            __hip_atomic_store(cnt, 0, __ATOMIC_RELAXED, __HIP_MEMORY_SCOPE_AGENT);
            __hip_atomic_store(gen, g + 1, __ATOMIC_RELEASE, __HIP_MEMORY_SCOPE_AGENT);
        } else {
            while (__hip_atomic_load(gen, __ATOMIC_ACQUIRE, __HIP_MEMORY_SCOPE_AGENT) == g)
                __builtin_amdgcn_s_sleep(2);
        }
        __threadfence();   // acquire
    }
    __syncthreads();
}

// ---------------------------------------------------------------------------
// One row-pair LSE step (round-8 validated math, absmax 0.0): prev-iterate
// shift, classic max-shifted fallback on wave-uniform guard.
// ---------------------------------------------------------------------------
__device__ __forceinline__ float2 pass_pair(
    const half8* __restrict__ r0, const half8* __restrict__ r1,
    const float* __restrict__ vk, int lane, float uo0, float uo1)
{
    const float M0 = LOGK2 - uo0 * K2;
    const float M1 = LOGK2 - uo1 * K2;
    float x0[16], x1[16];
#pragma unroll
    for (int k = 0; k < 2; ++k) {
        const int m_ = lane + (k << 6);
        half8 c0 = r0[m_], c1 = r1[m_];
        float4 va = ((const float4*)vk)[2 * m_];
        float4 vb = ((const float4*)vk)[2 * m_ + 1];
        float vv[8] = {va.x, va.y, va.z, va.w, vb.x, vb.y, vb.z, vb.w};
#pragma unroll
        for (int j = 0; j < 8; ++j) {
            x0[8 * k + j] = fmaf((float)c0[j], -K2, vv[j]);
            x1[8 * k + j] = fmaf((float)c1[j], -K2, vv[j]);
        }
    }
    float s0 = 0.f, s1 = 0.f;
#pragma unroll
    for (int i = 0; i < 16; ++i) { s0 += EXP2F(x0[i] - M0); s1 += EXP2F(x1[i] - M1); }
#pragma unroll
    for (int off = 32; off > 0; off >>= 1) {
        s0 += __shfl_xor(s0, off);
        s1 += __shfl_xor(s1, off);
    }
    float sh0 = M0, sh1 = M1;
    if (__builtin_expect(!(s0 >= 1e-27f && s0 <= 1e38f) ||
                         !(s1 >= 1e-27f && s1 <= 1e38f), 0)) {
        float m0 = x0[0], m1 = x1[0];
#pragma unroll
        for (int i = 1; i < 16; ++i) { m0 = fmaxf(m0, x0[i]); m1 = fmaxf(m1, x1[i]); }
#pragma unroll
        for (int off = 32; off > 0; off >>= 1) {
            m0 = fmaxf(m0, __shfl_xor(m0, off));
            m1 = fmaxf(m1, __shfl_xor(m1, off));
        }
        s0 = 0.f; s1 = 0.f;
#pragma unroll
        for (int i = 0; i < 16; ++i) { s0 += EXP2F(x0[i] - m0); s1 += EXP2F(x1[i] - m1); }
#pragma unroll
        for (int off = 32; off > 0; off >>= 1) {
            s0 += __shfl_xor(s0, off);
            s1 += __shfl_xor(s1, off);
        }
        sh0 = m0; sh1 = m1;
    }
    return make_float2(EPSf * (LOGK - (sh0 + LOG2F(s0)) * LN2f),
                       EPSf * (LOGK - (sh1 + LOG2F(s1)) * LN2f));
}

// ---------------------------------------------------------------------------
// Persistent Sinkhorn, PLAIN launch (no cooperative API): 512 blocks x 256.
// Co-residency by capacity: 2 blocks/CU needed, >=4 fit at this VGPR count.
// Block decode pins each batch's 32 blocks to one XCD (assuming blk%8->XCD
// round-robin; wrong mapping only costs speed, fences keep it correct):
//   xcd = blk&7, b = (xcd<<1)|((blk>>3)&1), l = blk>>4.
// Per-batch 32-block barrier between passes. No freeze logic in the loop;
// u/v snapshots per iteration, post-hoc T selection in cost_kernel.
// ---------------------------------------------------------------------------
__global__ __launch_bounds__(256, 2) void sinkhorn_all(
    const _Float16* __restrict__ C, const _Float16* __restrict__ CT,
    const float* __restrict__ zvec, float* __restrict__ usnap,
    float* __restrict__ vsnap, float* __restrict__ err,
    int* bcnt, int* bgen)
{
    __shared__ float ldsk[1024];
    __shared__ float red[4];
    const int tid  = threadIdx.x;
    const int wave = tid >> 6;
    const int lane = tid & 63;
    const int blk  = blockIdx.x;
    const int b    = ((blk & 7) << 1) | ((blk >> 3) & 1);
    const int l    = blk >> 4;
    int* cnt = bcnt + (b << 5);
    int* gen = bgen + (b << 5);

    const _Float16* Cb  = C  + ((size_t)b << 20);
    const _Float16* CTb = CT + ((size_t)b << 20);

    for (int it = 0; it < MAX_ITER; ++it) {
        const float* vold = it ? vsnap + (size_t)(it - 1) * 16384 + (b << 10) : zvec;
        const float* uold = it ? usnap + (size_t)(it - 1) * 16384 + (b << 10) : zvec;
        float* unew = usnap + (size_t)it * 16384 + (b << 10);
        float* vnew = vsnap + (size_t)it * 16384 + (b << 10);

        // ---- u pass: stage v*K2; 4 row-pairs per wave over C ----
        {
            float4 t4 = ((const float4*)vold)[tid];
            t4.x *= K2; t4.y *= K2; t4.z *= K2; t4.w *= K2;
            ((float4*)ldsk)[tid] = t4;
        }
        __syncthreads();
        float werr = 0.f;
#pragma unroll
        for (int pr = 0; pr < 4; ++pr) {
            const int r = (l << 5) + (wave << 3) + (pr << 1);
            const float uo0 = uold[r], uo1 = uold[r + 1];
            float2 nn = pass_pair((const half8*)(Cb + (size_t)r * NN),
                                  (const half8*)(Cb + (size_t)(r + 1) * NN),
                                  ldsk, lane, uo0, uo1);
            werr += fabsf(nn.x - uo0) + fabsf(nn.y - uo1);
            if (lane == 0) { unew[r] = nn.x; unew[r + 1] = nn.y; }
        }
        if (lane == 0) red[wave] = werr;
        __syncthreads();
        if (tid == 0)
            atomicAdd(&err[(b << 7) + it], red[0] + red[1] + red[2] + red[3]);
        group_barrier(cnt, gen);

        // ---- v pass: stage u_new*K2; 4 col-pairs per wave over CT ----
        {
            float4 t4 = ((const float4*)unew)[tid];
            t4.x *= K2; t4.y *= K2; t4.z *= K2; t4.w *= K2;
            ((float4*)ldsk)[tid] = t4;
        }
        __syncthreads();
#pragma unroll
        for (int pr = 0; pr < 4; ++pr) {
            const int r = (l << 5) + (wave << 3) + (pr << 1);
            float2 nn = pass_pair((const half8*)(CTb + (size_t)r * NN),
                                  (const half8*)(CTb + (size_t)(r + 1) * NN),
                                  ldsk, lane, vold[r], vold[r + 1]);
            if (lane == 0) { vnew[r] = nn.x; vnew[r + 1] = nn.y; }
        }
        group_barrier(cnt, gen);
    }
}

// ---------------------------------------------------------------------------
// T = first it with sum_b err[b][it] < 1.6 (else 99); then
// cost = mean_b sum_ij exp((u_i + v_j - C_ij)/eps) * C_ij from snapshot T.
// ---------------------------------------------------------------------------
__global__ __launch_bounds__(256) void cost_kernel(
    const _Float16* __restrict__ C, const float* __restrict__ usnap,
    const float* __restrict__ vsnap, const float* __restrict__ err,
    float* __restrict__ out)
{
    __shared__ float ldsv[1024];
    __shared__ float red[4];
    __shared__ int sT;
    const int tid = threadIdx.x, wave = tid >> 6, lane = tid & 63;
    const int b = blockIdx.x >> 5, l = blockIdx.x & 31;

    if (tid == 0) sT = MAX_ITER - 1;
    __syncthreads();
    if (tid < MAX_ITER) {
        float s = 0.f;
#pragma unroll
        for (int bb = 0; bb < 16; ++bb) s += err[(bb << 7) + tid];
        if (s < 1.6f) atomicMin(&sT, tid);
    }
    __syncthreads();
    const int T = sT;

    const float* u = usnap + (size_t)T * 16384 + (b << 10);
    const float* v = vsnap + (size_t)T * 16384 + (b << 10);
    ((float4*)ldsv)[tid] = ((const float4*)v)[tid];
    __syncthreads();

    const _Float16* Cb = C + ((size_t)b << 20);
    const float4* V4 = (const float4*)ldsv;
    float csum = 0.f;
    for (int rr = 0; rr < 8; ++rr) {
        const int row = (l << 5) + (wave << 3) + rr;
        const float ui = u[row];
        const half8* Crow = (const half8*)(Cb + (size_t)row * NN);
#pragma unroll
        for (int k = 0; k < 2; ++k) {
            const int m = lane + (k << 6);
            half8 c8 = Crow[m];
            float4 va = V4[2 * m];
            float4 vb4 = V4[2 * m + 1];
            float vv[8] = {va.x, va.y, va.z, va.w, vb4.x, vb4.y, vb4.z, vb4.w};
#pragma unroll
            for (int j = 0; j < 8; ++j) {
                float c = (float)c8[j];
                csum += EXP2F((ui + vv[j] - c) * K2) * c;
            }
        }
    }
#pragma unroll
    for (int off = 32; off > 0; off >>= 1) csum += __shfl_xor(csum, off);
    if (lane == 0) red[wave] = csum;
    __syncthreads();
    if (tid == 0)
        atomicAdd(out, (red[0] + red[1] + red[2] + red[3]) * (1.0f / 16.0f));
}

extern "C" void kernel_launch(void* const* d_in, const int* in_sizes, int n_in,
                              void* d_out, int out_size, void* d_ws, size_t ws_size,
                              hipStream_t stream) {
    const float* x = (const float*)d_in[0];  // output: [16,1024,32] fp32
    const float* y = (const float*)d_in[1];  // labels: [16,1024,32] fp32

    char* wsb = (char*)d_ws;
    _Float16* C  = (_Float16*)wsb;                       // 32 MB
    _Float16* CT = (_Float16*)(wsb + (32u << 20));       // 32 MB
    float* zvec  = (float*)(wsb + (64u << 20));          // 16384 (zeros)
    float* err   = zvec + 16384;                         // 16 x 128
    int*   bcnt  = (int*)(err + 2048);                   // 16 x 32
    int*   bgen  = bcnt + 512;                           // 16 x 32
    float* usnap = (float*)(bgen + 512);                 // 100 x 16384
    float* vsnap = usnap + 100 * 16384;                  // 100 x 16384
    float* out   = (float*)d_out;

    // zero zvec/err/bcnt/bgen (contiguous) + out
    (void)hipMemsetAsync(zvec, 0, (size_t)(16384 + 2048 + 512 + 512) * 4, stream);
    (void)hipMemsetAsync(out, 0, sizeof(float), stream);

    build_dist<<<dim3(16 * 64), dim3(256), 0, stream>>>(x, y, C);
    build_dist<<<dim3(16 * 64), dim3(256), 0, stream>>>(y, x, CT);

    sinkhorn_all<<<dim3(512), dim3(256), 0, stream>>>(
        C, CT, zvec, usnap, vsnap, err, bcnt, bgen);

    cost_kernel<<<dim3(512), dim3(256), 0, stream>>>(C, usnap, vsnap, err, out);
}

// Round 13
// 3224.698 us; speedup vs baseline: 3.3604x; 3.3604x over previous
//
#include <hip/hip_runtime.h>

// Problem constants (B=16, N=M=1024, D=32)
constexpr int   NN       = 1024;
constexpr float EPSf     = 1e-3f;
constexpr int   MAX_ITER = 100;

#define K2      1442.6950408889634f     // (1/eps) * log2(e)
#define LN2f    0.6931471805599453f
#define LOGK    (-6.9314616f)           // log(1/1024 + 1e-8)
#define LOGK2   (-9.9999852269f)        // LOGK * log2(e)

#define EXP2F(x) __builtin_amdgcn_exp2f(x)   // 2^x
#define LOG2F(x) __builtin_amdgcn_logf(x)    // log2(x)

typedef _Float16 half8 __attribute__((ext_vector_type(8)));

// Agent-scope relaxed atomics: coherent at the LLC, bypass per-XCD L2 —
// NO cache-flush fences required anywhere.
__device__ __forceinline__ float aload(const float* p) {
    return __hip_atomic_load(p, __ATOMIC_RELAXED, __HIP_MEMORY_SCOPE_AGENT);
}
__device__ __forceinline__ void astore(float* p, float v) {
    __hip_atomic_store(p, v, __ATOMIC_RELAXED, __HIP_MEMORY_SCOPE_AGENT);
}

// ---------------------------------------------------------------------------
// dist[b][p][q] = sum_d (A[b][p][d] - Bm[b][q][d])^2, stored fp16 (validated)
// ---------------------------------------------------------------------------
__global__ __launch_bounds__(256) void build_dist(
    const float* __restrict__ A, const float* __restrict__ Bm,
    _Float16* __restrict__ out)
{
    __shared__ float aLds[16 * 32];
    __shared__ float bLds[256 * 33];
    const int b  = blockIdx.x >> 6;
    const int pt = blockIdx.x & 63;
    const int t  = threadIdx.x;

    const float* Ab = A  + ((size_t)b * NN + pt * 16) * 32;
    const float* Bb = Bm + (size_t)b * NN * 32;

    if (t < 128) ((float4*)aLds)[t] = ((const float4*)Ab)[t];

    for (int qt = 0; qt < 4; ++qt) {
        __syncthreads();
        const float4* src = (const float4*)(Bb + qt * 256 * 32);
#pragma unroll
        for (int i = 0; i < 8; ++i) {
            int j = t + (i << 8);
            float4 val = src[j];
            int q = j >> 3, dd = (j & 7) << 2;
            float* dst = &bLds[q * 33 + dd];
            dst[0] = val.x; dst[1] = val.y; dst[2] = val.z; dst[3] = val.w;
        }
        __syncthreads();

        float br[32];
#pragma unroll
        for (int d = 0; d < 32; ++d) br[d] = bLds[t * 33 + d];

#pragma unroll
        for (int p = 0; p < 16; ++p) {
            float acc = 0.f;
#pragma unroll
            for (int d4 = 0; d4 < 8; ++d4) {
                float4 a4 = ((const float4*)(aLds + p * 32))[d4];
                float dx = a4.x - br[d4 * 4 + 0];
                float dy = a4.y - br[d4 * 4 + 1];
                float dz = a4.z - br[d4 * 4 + 2];
                float dw = a4.w - br[d4 * 4 + 3];
                acc += dx * dx + dy * dy + dz * dz + dw * dw;
            }
            out[((size_t)b * NN + pt * 16 + p) * NN + qt * 256 + t] = (_Float16)acc;
        }
    }
}

// ---------------------------------------------------------------------------
// Monotonic barrier over the 32 blocks of one batch, phase-counted.
// No fences: the leading __syncthreads() emits s_waitcnt vmcnt(0), draining
// this block's agent-atomic stores to the LLC before the arrival RMW.
// Last arrival of phase p (a == 32p+31) publishes gen = p+1.
// ---------------------------------------------------------------------------
__device__ __forceinline__ void group_barrier(int* cnt, int* gen, int phase)
{
    __syncthreads();
    if (threadIdx.x == 0) {
        int a = __hip_atomic_fetch_add(cnt, 1, __ATOMIC_RELAXED,
                                       __HIP_MEMORY_SCOPE_AGENT);
        if (a == (phase << 5) + 31) {
            __hip_atomic_store(gen, phase + 1, __ATOMIC_RELAXED,
                               __HIP_MEMORY_SCOPE_AGENT);
        } else {
            while (__hip_atomic_load(gen, __ATOMIC_RELAXED,
                                     __HIP_MEMORY_SCOPE_AGENT) <= phase)
                __builtin_amdgcn_s_sleep(2);
        }
    }
    __syncthreads();
}

// ---------------------------------------------------------------------------
// One row-pair LSE step (round-8 validated math, absmax 0.0): prev-iterate
// shift, classic max-shifted fallback on wave-uniform guard.
// ---------------------------------------------------------------------------
__device__ __forceinline__ float2 pass_pair(
    const half8* __restrict__ r0, const half8* __restrict__ r1,
    const float* __restrict__ vk, int lane, float uo0, float uo1)
{
    const float M0 = LOGK2 - uo0 * K2;
    const float M1 = LOGK2 - uo1 * K2;
    float x0[16], x1[16];
#pragma unroll
    for (int k = 0; k < 2; ++k) {
        const int m_ = lane + (k << 6);
        half8 c0 = r0[m_], c1 = r1[m_];
        float4 va = ((const float4*)vk)[2 * m_];
        float4 vb = ((const float4*)vk)[2 * m_ + 1];
        float vv[8] = {va.x, va.y, va.z, va.w, vb.x, vb.y, vb.z, vb.w};
#pragma unroll
        for (int j = 0; j < 8; ++j) {
            x0[8 * k + j] = fmaf((float)c0[j], -K2, vv[j]);
            x1[8 * k + j] = fmaf((float)c1[j], -K2, vv[j]);
        }
    }
    float s0 = 0.f, s1 = 0.f;
#pragma unroll
    for (int i = 0; i < 16; ++i) { s0 += EXP2F(x0[i] - M0); s1 += EXP2F(x1[i] - M1); }
#pragma unroll
    for (int off = 32; off > 0; off >>= 1) {
        s0 += __shfl_xor(s0, off);
        s1 += __shfl_xor(s1, off);
    }
    float sh0 = M0, sh1 = M1;
    if (__builtin_expect(!(s0 >= 1e-27f && s0 <= 1e38f) ||
                         !(s1 >= 1e-27f && s1 <= 1e38f), 0)) {
        float m0 = x0[0], m1 = x1[0];
#pragma unroll
        for (int i = 1; i < 16; ++i) { m0 = fmaxf(m0, x0[i]); m1 = fmaxf(m1, x1[i]); }
#pragma unroll
        for (int off = 32; off > 0; off >>= 1) {
            m0 = fmaxf(m0, __shfl_xor(m0, off));
            m1 = fmaxf(m1, __shfl_xor(m1, off));
        }
        s0 = 0.f; s1 = 0.f;
#pragma unroll
        for (int i = 0; i < 16; ++i) { s0 += EXP2F(x0[i] - m0); s1 += EXP2F(x1[i] - m1); }
#pragma unroll
        for (int off = 32; off > 0; off >>= 1) {
            s0 += __shfl_xor(s0, off);
            s1 += __shfl_xor(s1, off);
        }
        sh0 = m0; sh1 = m1;
    }
    return make_float2(EPSf * (LOGK - (sh0 + LOG2F(s0)) * LN2f),
                       EPSf * (LOGK - (sh1 + LOG2F(s1)) * LN2f));
}

// ---------------------------------------------------------------------------
// Persistent Sinkhorn, PLAIN launch: 512 blocks x 256 (co-residency proven
// in round 12). All cross-block data (u/v snapshots) moves via agent-scope
// atomics; barriers are fence-free. Block decode XCD-pins each batch.
// ---------------------------------------------------------------------------
__global__ __launch_bounds__(256, 2) void sinkhorn_all(
    const _Float16* __restrict__ C, const _Float16* __restrict__ CT,
    const float* __restrict__ zvec, float* __restrict__ usnap,
    float* __restrict__ vsnap, float* __restrict__ err,
    int* bcnt, int* bgen)
{
    __shared__ float ldsk[1024];
    __shared__ float red[4];
    const int tid  = threadIdx.x;
    const int wave = tid >> 6;
    const int lane = tid & 63;
    const int blk  = blockIdx.x;
    const int b    = ((blk & 7) << 1) | ((blk >> 3) & 1);
    const int l    = blk >> 4;
    int* cnt = bcnt + (b << 5);
    int* gen = bgen + (b << 5);
    int phase = 0;

    const _Float16* Cb  = C  + ((size_t)b << 20);
    const _Float16* CTb = CT + ((size_t)b << 20);

    for (int it = 0; it < MAX_ITER; ++it) {
        const float* vold = it ? vsnap + (size_t)(it - 1) * 16384 + (b << 10) : zvec;
        const float* uold = it ? usnap + (size_t)(it - 1) * 16384 + (b << 10) : zvec;
        float* unew = usnap + (size_t)it * 16384 + (b << 10);
        float* vnew = vsnap + (size_t)it * 16384 + (b << 10);

        // ---- u pass: stage v*K2 (atomic loads); 4 row-pairs/wave over C ----
        {
            const int i0 = tid << 2;
            float a0 = aload(vold + i0),     a1 = aload(vold + i0 + 1);
            float a2 = aload(vold + i0 + 2), a3 = aload(vold + i0 + 3);
            ldsk[i0] = a0 * K2; ldsk[i0 + 1] = a1 * K2;
            ldsk[i0 + 2] = a2 * K2; ldsk[i0 + 3] = a3 * K2;
        }
        __syncthreads();
        float werr = 0.f;
#pragma unroll
        for (int pr = 0; pr < 4; ++pr) {
            const int r = (l << 5) + (wave << 3) + (pr << 1);
            const float uo0 = aload(uold + r), uo1 = aload(uold + r + 1);
            float2 nn = pass_pair((const half8*)(Cb + (size_t)r * NN),
                                  (const half8*)(Cb + (size_t)(r + 1) * NN),
                                  ldsk, lane, uo0, uo1);
            werr += fabsf(nn.x - uo0) + fabsf(nn.y - uo1);
            if (lane == 0) { astore(unew + r, nn.x); astore(unew + r + 1, nn.y); }
        }
        if (lane == 0) red[wave] = werr;
        __syncthreads();
        if (tid == 0)
            atomicAdd(&err[(b << 7) + it], red[0] + red[1] + red[2] + red[3]);
        group_barrier(cnt, gen, phase++);

        // ---- v pass: stage u_new*K2 (atomic loads); over CT ----
        {
            const int i0 = tid << 2;
            float a0 = aload(unew + i0),     a1 = aload(unew + i0 + 1);
            float a2 = aload(unew + i0 + 2), a3 = aload(unew + i0 + 3);
            ldsk[i0] = a0 * K2; ldsk[i0 + 1] = a1 * K2;
            ldsk[i0 + 2] = a2 * K2; ldsk[i0 + 3] = a3 * K2;
        }
        __syncthreads();
#pragma unroll
        for (int pr = 0; pr < 4; ++pr) {
            const int r = (l << 5) + (wave << 3) + (pr << 1);
            const float vo0 = aload(vold + r), vo1 = aload(vold + r + 1);
            float2 nn = pass_pair((const half8*)(CTb + (size_t)r * NN),
                                  (const half8*)(CTb + (size_t)(r + 1) * NN),
                                  ldsk, lane, vo0, vo1);
            if (lane == 0) { astore(vnew + r, nn.x); astore(vnew + r + 1, nn.y); }
        }
        group_barrier(cnt, gen, phase++);
    }
}

// ---------------------------------------------------------------------------
// T = first it with sum_b err[b][it] < 1.6 (else 99); then
// cost = mean_b sum_ij exp((u_i + v_j - C_ij)/eps) * C_ij from snapshot T.
// ---------------------------------------------------------------------------
__global__ __launch_bounds__(256) void cost_kernel(
    const _Float16* __restrict__ C, const float* __restrict__ usnap,
    const float* __restrict__ vsnap, const float* __restrict__ err,
    float* __restrict__ out)
{
    __shared__ float ldsv[1024];
    __shared__ float red[4];
    __shared__ int sT;
    const int tid = threadIdx.x, wave = tid >> 6, lane = tid & 63;
    const int b = blockIdx.x >> 5, l = blockIdx.x & 31;

    if (tid == 0) sT = MAX_ITER - 1;
    __syncthreads();
    if (tid < MAX_ITER) {
        float s = 0.f;
#pragma unroll
        for (int bb = 0; bb < 16; ++bb) s += err[(bb << 7) + tid];
        if (s < 1.6f) atomicMin(&sT, tid);
    }
    __syncthreads();
    const int T = sT;

    const float* u = usnap + (size_t)T * 16384 + (b << 10);
    const float* v = vsnap + (size_t)T * 16384 + (b << 10);
    ((float4*)ldsv)[tid] = ((const float4*)v)[tid];
    __syncthreads();

    const _Float16* Cb = C + ((size_t)b << 20);
    const float* ub = u;
    const float4* V4 = (const float4*)ldsv;
    float csum = 0.f;
    for (int rr = 0; rr < 8; ++rr) {
        const int row = (l << 5) + (wave << 3) + rr;
        const float ui = ub[row];
        const half8* Crow = (const half8*)(Cb + (size_t)row * NN);
#pragma unroll
        for (int k = 0; k < 2; ++k) {
            const int m = lane + (k << 6);
            half8 c8 = Crow[m];
            float4 va = V4[2 * m];
            float4 vb4 = V4[2 * m + 1];
            float vv[8] = {va.x, va.y, va.z, va.w, vb4.x, vb4.y, vb4.z, vb4.w};
#pragma unroll
            for (int j = 0; j < 8; ++j) {
                float c = (float)c8[j];
                csum += EXP2F((ui + vv[j] - c) * K2) * c;
            }
        }
    }
#pragma unroll
    for (int off = 32; off > 0; off >>= 1) csum += __shfl_xor(csum, off);
    if (lane == 0) red[wave] = csum;
    __syncthreads();
    if (tid == 0)
        atomicAdd(out, (red[0] + red[1] + red[2] + red[3]) * (1.0f / 16.0f));
}

extern "C" void kernel_launch(void* const* d_in, const int* in_sizes, int n_in,
                              void* d_out, int out_size, void* d_ws, size_t ws_size,
                              hipStream_t stream) {
    const float* x = (const float*)d_in[0];  // output: [16,1024,32] fp32
    const float* y = (const float*)d_in[1];  // labels: [16,1024,32] fp32

    char* wsb = (char*)d_ws;
    _Float16* C  = (_Float16*)wsb;                       // 32 MB
    _Float16* CT = (_Float16*)(wsb + (32u << 20));       // 32 MB
    float* zvec  = (float*)(wsb + (64u << 20));          // 16384 (zeros)
    float* err   = zvec + 16384;                         // 16 x 128
    int*   bcnt  = (int*)(err + 2048);                   // 16 x 32
    int*   bgen  = bcnt + 512;                           // 16 x 32
    float* usnap = (float*)(bgen + 512);                 // 100 x 16384
    float* vsnap = usnap + 100 * 16384;                  // 100 x 16384
    float* out   = (float*)d_out;

    // zero zvec/err/bcnt/bgen (contiguous) + out
    (void)hipMemsetAsync(zvec, 0, (size_t)(16384 + 2048 + 512 + 512) * 4, stream);
    (void)hipMemsetAsync(out, 0, sizeof(float), stream);

    build_dist<<<dim3(16 * 64), dim3(256), 0, stream>>>(x, y, C);
    build_dist<<<dim3(16 * 64), dim3(256), 0, stream>>>(y, x, CT);

    sinkhorn_all<<<dim3(512), dim3(256), 0, stream>>>(
        C, CT, zvec, usnap, vsnap, err, bcnt, bgen);

    cost_kernel<<<dim3(512), dim3(256), 0, stream>>>(C, usnap, vsnap, err, out);
}